// Round 9
// baseline (5062.770 us; speedup 1.0000x reference)
//
#include <hip/hip_runtime.h>

#define D      128
#define NINIT  100000
#define LVLS   64
#define M      4096
#define NRULES 256
#define NTOT   (NINIT + LVLS * M)
#define NTHR   512
#define TILE   32

typedef __attribute__((ext_vector_type(8))) short short8;   // 8 bf16 = 4 VGPRs
typedef __attribute__((ext_vector_type(4))) float floatx4;  // MFMA accumulator

// ---------------------------------------------------------------------------
// ws layout (bytes):
//   0      : sums[2] fp32
//   128    : barrier cnt (u32), barrier gen (u32)       (own cacheline)
//   512    : lvlcnt u32[LVLS]  per-level arrival counters (256 B, 1-2 lines)
//   4096   : store  bf16 [NTOT][128]          (92,708,864 B)
//   SI_OFF : sorted_idx int [LVLS][M]          (1,048,576 B)
//   RO_OFF : rule_off  int [LVLS][NRULES+1]       (65,792 B)
// ---------------------------------------------------------------------------
#define CNT_OFF 512
#define ST_OFF  4096
#define SI_OFF (ST_OFF + (size_t)NTOT * D * 2)
#define RO_OFF (SI_OFF + (size_t)LVLS * M * 4)

#define CBAR() asm volatile("" ::: "memory")

__device__ __forceinline__ unsigned short f2bf(float x) {  // RNE fp32->bf16
  unsigned u = __float_as_uint(x);
  u += 0x7fffu + ((u >> 16) & 1u);
  return (unsigned short)(u >> 16);
}

__device__ __forceinline__ float softplusf(float x) {
  return fmaxf(x, 0.f) + log1pf(expf(-fabsf(x)));
}

// --- LLC-coherent (cross-XCD) primitives. SYSTEM-scope relaxed atomics emit
// sc0 sc1 accesses: stores write through to the Infinity Cache (coherence
// point for all 8 XCDs), loads bypass L1/L2 and read it directly.
__device__ __forceinline__ void st_sys(unsigned* p, unsigned v) {
  __hip_atomic_store(p, v, __ATOMIC_RELAXED, __HIP_MEMORY_SCOPE_SYSTEM);
}
__device__ __forceinline__ void st_sys64(unsigned long long* p,
                                         unsigned long long v) {
  __hip_atomic_store(p, v, __ATOMIC_RELAXED, __HIP_MEMORY_SCOPE_SYSTEM);
}
__device__ __forceinline__ unsigned ld_sys(const unsigned* p) {
  return __hip_atomic_load(p, __ATOMIC_RELAXED, __HIP_MEMORY_SCOPE_SYSTEM);
}
__device__ __forceinline__ void add_sys(unsigned* p, unsigned v) {
  (void)__hip_atomic_fetch_add(p, v, __ATOMIC_RELAXED,
                               __HIP_MEMORY_SCOPE_SYSTEM);
}
// Spin until level counter complete; capped (bug -> wrong answer, not hang).
__device__ __forceinline__ void wait_lvl(const unsigned* c) {
  int guard = 1 << 17;
  while (__builtin_expect(ld_sys(c) < (unsigned)M, 0) && --guard)
    __builtin_amdgcn_s_sleep(1);
  CBAR();
}

// Light grid barrier: fence-free. Valid because all cross-block data is
// written via st_sys (already at the LLC when __syncthreads drains vmcnt)
// and consumers never cached those lines beforehand. Used ONCE (after init).
__device__ __forceinline__ void gbar_light(unsigned* bcnt, unsigned* bgen) {
  __syncthreads();  // drains vmcnt: this block's sc-stores are at the LLC
  if (threadIdx.x == 0) {
    unsigned g = ld_sys(bgen);
    unsigned v = __hip_atomic_fetch_add(bcnt, 1u, __ATOMIC_RELAXED,
                                        __HIP_MEMORY_SCOPE_SYSTEM);
    if (v == gridDim.x - 1) {
      st_sys(bcnt, 0u);
      st_sys(bgen, g + 1u);
    } else {
      int guard = 1 << 22;
      while (ld_sys(bgen) == g && --guard) __builtin_amdgcn_s_sleep(2);
    }
  }
  __syncthreads();
}

// Cursor over rule r's 32-node tiles across all levels (skips empty levels).
__device__ __forceinline__ bool adv_cursor(int r, const int* __restrict__ ro,
                                           int& l, int& t0, int& off, int& cnt) {
  t0 += TILE;
  while (t0 >= cnt) {
    if (++l >= LVLS) return false;
    off = ro[l * (NRULES + 1) + r];
    cnt = ro[l * (NRULES + 1) + r + 1] - off;
    t0 = 0;
  }
  return true;
}

// One cooperative kernel. Block r owns rule r (B-fragments persistent in 32
// VGPRs). 32-node tiles, depth-3 pipeline. Synchronization = per-LEVEL
// arrival counters in one hot 256B LLC region: readiness test is
// cnt[(par-NINIT)>>12] >= M; publication is ONE per-wave atomicAdd after a
// counted vmcnt. Derived loss fused in-loop; init loss unsynchronized tail.
__global__ __launch_bounds__(NTHR, 2) void fused_kernel(
    const float* __restrict__ thax_table, const float* __restrict__ sine_table,
    const float* __restrict__ rule_W, const float* __restrict__ rule_b,
    const float* __restrict__ eval_w, const float* __restrict__ eval_b,
    const float* __restrict__ pos, const float* __restrict__ neg,
    const int* __restrict__ init_thax, const int* __restrict__ init_sine,
    const int* __restrict__ parents,  // [LVLS][M][2]
    const int* __restrict__ rules,    // [LVLS][M]
    unsigned short* __restrict__ store, int* __restrict__ sorted_idx,
    int* __restrict__ rule_off, unsigned* __restrict__ lvlcnt,
    float* __restrict__ sums, unsigned* __restrict__ bvars,
    float* __restrict__ out) {
  __shared__ unsigned short pe[TILE * 264];  // gather tile: 32 x 256 + pad
  __shared__ unsigned short ot[TILE * 136];  // output tile: 32 x 128 + pad
  __shared__ int s_sid[2][TILE];
  __shared__ int s_cnt[NRULES];
  __shared__ int s_base[NRULES + 1];
  __shared__ float racc[3];

  unsigned* bcnt = bvars;
  unsigned* bgen = bvars + 1;

  const int r = blockIdx.x;
  const int tid = threadIdx.x;
  const int wave = tid >> 6, lane = tid & 63;
  const int col = (wave << 4) + (lane & 15);
  const int node = tid >> 4;   // 0..31: staged node
  const int segq = tid & 15;   // 16B chunk within each parent's 256B row
  const int gid = r * NTHR + tid;
  const int gthreads = NRULES * NTHR;

  // Loss accumulators (fused derived loss + init tail).
  float a_loss = 0.f, a_pos = 0.f, a_neg = 0.f;
  const float eb = eval_b[0];
  float w8[8];
  {
    float4 wA = ((const float4*)eval_w)[segq * 2];
    float4 wB = ((const float4*)eval_w)[segq * 2 + 1];
    w8[0] = wA.x; w8[1] = wA.y; w8[2] = wA.z; w8[3] = wA.w;
    w8[4] = wB.x; w8[5] = wB.y; w8[6] = wB.z; w8[7] = wB.w;
  }

  // ---- Phase A1: rule-r weight fragments, fp32 global -> bf16 VGPRs (once).
  short8 bf[8];
  {
    const float* Wr = rule_W + (size_t)r * (2 * D * D);
    const int krow_base = (lane >> 4) * 8;
#pragma unroll
    for (int ks = 0; ks < 8; ++ks) {
      union { short8 s; unsigned short us[8]; } c;
#pragma unroll
      for (int j = 0; j < 8; ++j)
        c.us[j] = f2bf(Wr[(size_t)(ks * 32 + krow_base + j) * D + col]);
      bf[ks] = c.s;
    }
  }
  const float bias = rule_b[r * D + col];

  // ---- Phase A2: counting-sort nodes by rule (blocks 0..63, one level each).
  if (r < LVLS) {
    const int l = r;
    const int* rl = rules + (size_t)l * M;
    if (tid < NRULES) s_cnt[tid] = 0;
    __syncthreads();
    for (int m = tid; m < M; m += NTHR) atomicAdd(&s_cnt[rl[m]], 1);
    __syncthreads();
    if (tid == 0) {
      int run = 0;
      for (int q = 0; q < NRULES; ++q) { s_base[q] = run; run += s_cnt[q]; }
      s_base[NRULES] = run;
    }
    __syncthreads();
    if (tid < NRULES) {
      st_sys((unsigned*)&rule_off[(size_t)l * (NRULES + 1) + tid],
             (unsigned)s_base[tid]);
      s_cnt[tid] = s_base[tid];
    }
    if (tid == 0)
      st_sys((unsigned*)&rule_off[(size_t)l * (NRULES + 1) + NRULES],
             (unsigned)M);
    __syncthreads();
    for (int m = tid; m < M; m += NTHR) {
      int p = atomicAdd(&s_cnt[rl[m]], 1);
      st_sys((unsigned*)&sorted_idx[(size_t)l * M + p], (unsigned)m);
    }
  }

  // ---- Phase A3: init-node embeddings (all blocks, grid-stride, sc-qwords).
  for (int idx = gid; idx < NINIT * 16; idx += gthreads) {
    int nd = idx >> 4, sg = idx & 15;
    const float4* t = (const float4*)(thax_table + (size_t)init_thax[nd] * D) + sg * 2;
    const float4* s = (const float4*)(sine_table + (size_t)init_sine[nd] * D) + sg * 2;
    float4 a0 = t[0], a1 = t[1], b0 = s[0], b1 = s[1];
    float v[8] = {a0.x + b0.x, a0.y + b0.y, a0.z + b0.z, a0.w + b0.w,
                  a1.x + b1.x, a1.y + b1.y, a1.z + b1.z, a1.w + b1.w};
    unsigned p0 = (unsigned)f2bf(v[0]) | ((unsigned)f2bf(v[1]) << 16);
    unsigned p1 = (unsigned)f2bf(v[2]) | ((unsigned)f2bf(v[3]) << 16);
    unsigned p2 = (unsigned)f2bf(v[4]) | ((unsigned)f2bf(v[5]) << 16);
    unsigned p3 = (unsigned)f2bf(v[6]) | ((unsigned)f2bf(v[7]) << 16);
    unsigned long long* dst =
        (unsigned long long*)(store + (size_t)nd * D + sg * 8);
    st_sys64(dst + 0, (unsigned long long)p0 | ((unsigned long long)p1 << 32));
    st_sys64(dst + 1, (unsigned long long)p2 | ((unsigned long long)p3 << 32));
  }

  // ---- Phase A4: pos/neg sums.
  {
    float sp = 0.f, sn = 0.f;
    for (int i = gid; i < NTOT; i += gthreads) {
      sp += pos[i];
      sn += neg[i];
    }
    for (int m = 32; m; m >>= 1) {
      sp += __shfl_xor(sp, m, 64);
      sn += __shfl_xor(sn, m, 64);
    }
    if (lane == 0) {
      atomicAdd(&sums[0], sp);
      atomicAdd(&sums[1], sn);
    }
  }

  gbar_light(bcnt, bgen);  // publish sort/init/sums (all sc-written)

  const float pw = sums[1] / sums[0];  // valid after the barrier

  // ---- Level loop: depth-3 tile pipeline (A=compute, B=rows, C=counter
  // polls, D=idx). Readiness = lvlcnt[parent_level] >= M.
  int lL = -1, t0L = 0, offL = 0, cntL = 0;

  bool validA = adv_cursor(r, rule_off, lL, t0L, offL, cntL);
  int lA = lL, t0A = t0L, cntA = cntL;
  int parA0 = 0, parA1 = 0;
  bool lateA0 = false, lateA1 = false;
  unsigned reA0 = M, reA1 = M;
  float pPosA = 0.f, pNegA = 0.f;
  uint4 gA0 = {0, 0, 0, 0}, gA1 = {0, 0, 0, 0};
  if (validA) {
    int gj = t0A + node; if (gj > cntA - 1) gj = cntA - 1;
    int sid = sorted_idx[(size_t)lA * M + offL + gj];
    parA0 = parents[((size_t)lA * M + sid) * 2 + 0];
    parA1 = parents[((size_t)lA * M + sid) * 2 + 1];
    pPosA = pos[NINIT + lA * M + sid];
    pNegA = neg[NINIT + lA * M + sid];
    if (parA0 >= NINIT) wait_lvl(lvlcnt + ((parA0 - NINIT) >> 12));
    if (parA1 >= NINIT) wait_lvl(lvlcnt + ((parA1 - NINIT) >> 12));
    gA0 = *(const uint4*)(store + (size_t)parA0 * D + segq * 8);
    gA1 = *(const uint4*)(store + (size_t)parA1 * D + segq * 8);
    if (segq == 0) s_sid[0][node] = sid;
  }

  bool validB = validA && adv_cursor(r, rule_off, lL, t0L, offL, cntL);
  int lB = lL, t0B = t0L, cntB = cntL;
  int sidB = 0, parB0 = 0, parB1 = 0;
  unsigned fB0 = M, fB1 = M;
  if (validB) {
    int gj = t0B + node; if (gj > cntB - 1) gj = cntB - 1;
    sidB = sorted_idx[(size_t)lB * M + offL + gj];
    parB0 = parents[((size_t)lB * M + sidB) * 2 + 0];
    parB1 = parents[((size_t)lB * M + sidB) * 2 + 1];
    fB0 = parB0 >= NINIT ? ld_sys(lvlcnt + ((parB0 - NINIT) >> 12)) : M;
    fB1 = parB1 >= NINIT ? ld_sys(lvlcnt + ((parB1 - NINIT) >> 12)) : M;
  }

  bool validC = validB && adv_cursor(r, rule_off, lL, t0L, offL, cntL);
  int lC = lL, t0C = t0L, cntC = cntL;
  int sidC = 0, parC0 = 0, parC1 = 0;
  if (validC) {
    int gj = t0C + node; if (gj > cntC - 1) gj = cntC - 1;
    sidC = sorted_idx[(size_t)lC * M + offL + gj];
    parC0 = parents[((size_t)lC * M + sidC) * 2 + 0];
    parC1 = parents[((size_t)lC * M + sidC) * 2 + 1];
  }

  bool validD = validC && adv_cursor(r, rule_off, lL, t0L, offL, cntL);
  int lD = lL, t0D = t0L, offD = offL, cntD = cntL;

  int p = 0;
  while (validA) {
    // (0) late-resolve A: combined spin on the HOT counter lines (one vmem
    // per spin iteration for all lanes), then re-gather.
    if (lateA0 || lateA1) {
      bool n0 = lateA0 && (reA0 < (unsigned)M);
      bool n1 = lateA1 && (reA1 < (unsigned)M);
      if (n0 || n1) {
        int guard = 1 << 17;
        while (guard--) {
          unsigned f0 = n0 ? ld_sys(lvlcnt + ((parA0 - NINIT) >> 12)) : M;
          unsigned f1 = n1 ? ld_sys(lvlcnt + ((parA1 - NINIT) >> 12)) : M;
          if (f0 >= (unsigned)M && f1 >= (unsigned)M) break;
          __builtin_amdgcn_s_sleep(1);
        }
      }
      CBAR();
      if (lateA0) gA0 = *(const uint4*)(store + (size_t)parA0 * D + segq * 8);
      if (lateA1) gA1 = *(const uint4*)(store + (size_t)parA1 * D + segq * 8);
    }

    // (1) stage pe
    *(uint4*)(pe + node * 264 + segq * 8) = gA0;
    *(uint4*)(pe + node * 264 + 128 + segq * 8) = gA1;
    __syncthreads();
    if (validB && segq == 0) s_sid[p ^ 1][node] = sidB;

    // (2) 16 MFMA (two 16-node halves) + ReLU/bias -> transpose tile
    floatx4 acc0 = {0.f, 0.f, 0.f, 0.f}, acc1 = {0.f, 0.f, 0.f, 0.f};
#pragma unroll
    for (int ks = 0; ks < 8; ++ks) {
      short8 a0 = *(const short8*)(pe + (lane & 15) * 264 + ks * 32 + (lane >> 4) * 8);
      short8 a1 = *(const short8*)(pe + (16 + (lane & 15)) * 264 + ks * 32 + (lane >> 4) * 8);
      acc0 = __builtin_amdgcn_mfma_f32_16x16x32_bf16(a0, bf[ks], acc0, 0, 0, 0);
      acc1 = __builtin_amdgcn_mfma_f32_16x16x32_bf16(a1, bf[ks], acc1, 0, 0, 0);
    }
#pragma unroll
    for (int reg = 0; reg < 4; ++reg) {
      int row = (lane >> 4) * 4 + reg;
      float v0 = acc0[reg] + bias;
      float v1 = acc1[reg] + bias;
      ot[row * 136 + col] = f2bf(v0 > 0.f ? v0 : 0.f);
      ot[(16 + row) * 136 + col] = f2bf(v1 > 0.f ? v1 : 0.f);
    }
    __syncthreads();

    // (3) rows(A): wave w owns nodes {w,w+8,w+16,w+24}; S in-range stores.
    const int n_baseA = NINIT + lA * M;
    int S = 0;
#pragma unroll
    for (int k = 0; k < 4; ++k) {
      int nd = wave + 8 * k;
      if ((t0A + nd) < cntA) {  // wave-uniform
        st_sys((unsigned*)(store + (size_t)(n_baseA + s_sid[p][nd]) * D) + lane,
               *(const unsigned*)(ot + nd * 136 + lane * 2));
        ++S;
      }
    }
    CBAR();  // prefetches below stay AFTER the row stores in issue order

    // (4) prefetches (in flight across the counted drain). Gathers(B) use a
    // dummy (row 0) address for unready lanes -> no stale line ever cached.
    bool lateB0 = validB && parB0 >= NINIT && fB0 < (unsigned)M;
    bool lateB1 = validB && parB1 >= NINIT && fB1 < (unsigned)M;
    uint4 gB0, gB1;
    float pPosB = 0.f, pNegB = 0.f;
    {
      const unsigned short* a0 =
          (validB && !lateB0) ? store + (size_t)parB0 * D : store;
      const unsigned short* a1 =
          (validB && !lateB1) ? store + (size_t)parB1 * D : store;
      gB0 = *(const uint4*)(a0 + segq * 8);
      gB1 = *(const uint4*)(a1 + segq * 8);
    }
    if (validB) {
      pPosB = pos[NINIT + lB * M + sidB];
      pNegB = neg[NINIT + lB * M + sidB];
    }
    int sidD = 0, parD0 = 0, parD1 = 0;
    if (validD) {
      int gj = t0D + node; if (gj > cntD - 1) gj = cntD - 1;
      sidD = sorted_idx[(size_t)lD * M + offD + gj];
      parD0 = parents[((size_t)lD * M + sidD) * 2 + 0];
      parD1 = parents[((size_t)lD * M + sidD) * 2 + 1];
    }
    unsigned fC0 = M, fC1 = M;
    if (validC) {
      fC0 = parC0 >= NINIT ? ld_sys(lvlcnt + ((parC0 - NINIT) >> 12)) : M;
      fC1 = parC1 >= NINIT ? ld_sys(lvlcnt + ((parC1 - NINIT) >> 12)) : M;
    }
    // End re-poll of late B-parents' counters (producers publish ~now).
    unsigned reB0 = M, reB1 = M;
    if (lateB0) reB0 = ld_sys(lvlcnt + ((parB0 - NINIT) >> 12));
    if (lateB1) reB1 = ld_sys(lvlcnt + ((parB1 - NINIT) >> 12));
    CBAR();

    // (5) counted drain + ONE atomic publish. When validB, >=4 vmem loads
    // (gB0,gB1,pPosB,pNegB) were issued after the S row stores; vmcnt(4)
    // retires the rows (oldest-first) while prefetches stay in flight.
    if (validB) asm volatile("s_waitcnt vmcnt(4)" ::: "memory");
    else        asm volatile("s_waitcnt vmcnt(0)" ::: "memory");
    if (lane == 0 && S) add_sys(lvlcnt + lA, (unsigned)S);
    CBAR();  // publish issued before any later spin

    // (L) fused derived-node loss from the ot tile (pure VALU, off-chain).
    {
      const uint4 u = *(const uint4*)(ot + node * 136 + segq * 8);
      float pd = __uint_as_float(u.x << 16) * w8[0] +
                 __uint_as_float(u.x & 0xffff0000u) * w8[1] +
                 __uint_as_float(u.y << 16) * w8[2] +
                 __uint_as_float(u.y & 0xffff0000u) * w8[3] +
                 __uint_as_float(u.z << 16) * w8[4] +
                 __uint_as_float(u.z & 0xffff0000u) * w8[5] +
                 __uint_as_float(u.w << 16) * w8[6] +
                 __uint_as_float(u.w & 0xffff0000u) * w8[7];
      pd += __shfl_xor(pd, 1, 64);
      pd += __shfl_xor(pd, 2, 64);
      pd += __shfl_xor(pd, 4, 64);
      pd += __shfl_xor(pd, 8, 64);
      if (segq == 0 && (t0A + node) < cntA) {
        float logit = pd + eb;
        float tot = pPosA + pNegA, y = pPosA / tot;
        a_loss += tot * (pw * y * softplusf(-logit) +
                         (1.f - y) * softplusf(logit));
        if (logit >= 0.f) a_pos += pPosA; else a_neg += pNegA;
      }
    }

    // (6) shift pipeline slots
    gA0 = gB0; gA1 = gB1; lateA0 = lateB0; lateA1 = lateB1;
    reA0 = reB0; reA1 = reB1;
    parA0 = parB0; parA1 = parB1;
    pPosA = pPosB; pNegA = pNegB;
    lA = lB; t0A = t0B; cntA = cntB; validA = validB;
    sidB = sidC; parB0 = parC0; parB1 = parC1; fB0 = fC0; fB1 = fC1;
    lB = lC; t0B = t0C; cntB = cntC; validB = validC;
    sidC = sidD; parC0 = parD0; parC1 = parD1;
    lC = lD; t0C = t0D; cntC = cntD; validC = validD;
    validD = validC && adv_cursor(r, rule_off, lL, t0L, offL, cntL);
    lD = lL; t0D = t0L; offD = offL; cntD = cntL;
    p ^= 1;
  }

  // ---- Init-node loss tail: unsynchronized per-block stream.
  {
    const float4* wv = (const float4*)eval_w;
    for (int nd = gid; nd < NINIT; nd += gthreads) {
      const uint4* v = (const uint4*)(store + (size_t)nd * D);
      float dot = 0.f;
#pragma unroll
      for (int k = 0; k < 16; ++k) {
        uint4 u = v[k];
        float4 w0 = wv[k * 2], w1 = wv[k * 2 + 1];
        dot += __uint_as_float(u.x << 16) * w0.x +
               __uint_as_float(u.x & 0xffff0000u) * w0.y +
               __uint_as_float(u.y << 16) * w0.z +
               __uint_as_float(u.y & 0xffff0000u) * w0.w +
               __uint_as_float(u.z << 16) * w1.x +
               __uint_as_float(u.z & 0xffff0000u) * w1.y +
               __uint_as_float(u.w << 16) * w1.z +
               __uint_as_float(u.w & 0xffff0000u) * w1.w;
      }
      float logit = dot + eb;
      float pp = pos[nd], nn = neg[nd];
      float tot = pp + nn, y = pp / tot;
      a_loss += tot * (pw * y * softplusf(-logit) + (1.f - y) * softplusf(logit));
      if (logit >= 0.f) a_pos += pp; else a_neg += nn;
    }
  }

  // ---- Final reduction: wave shfl -> block LDS -> device atomics.
  for (int m = 32; m; m >>= 1) {
    a_loss += __shfl_xor(a_loss, m, 64);
    a_pos  += __shfl_xor(a_pos,  m, 64);
    a_neg  += __shfl_xor(a_neg,  m, 64);
  }
  if (tid == 0) { racc[0] = 0.f; racc[1] = 0.f; racc[2] = 0.f; }
  __syncthreads();
  if (lane == 0) {
    atomicAdd(&racc[0], a_loss);
    atomicAdd(&racc[1], a_pos);
    atomicAdd(&racc[2], a_neg);
  }
  __syncthreads();
  if (tid == 0) {
    atomicAdd(&out[0], racc[0]);
    atomicAdd(&out[1], racc[1]);
    atomicAdd(&out[2], racc[2]);
  }
}

extern "C" void kernel_launch(void* const* d_in, const int* in_sizes, int n_in,
                              void* d_out, int out_size, void* d_ws, size_t ws_size,
                              hipStream_t stream) {
  const float* thax_table = (const float*)d_in[0];
  const float* sine_table = (const float*)d_in[1];
  const float* rule_W     = (const float*)d_in[2];
  const float* rule_b     = (const float*)d_in[3];
  const float* eval_w     = (const float*)d_in[4];
  const float* eval_b     = (const float*)d_in[5];
  const float* pos_vals   = (const float*)d_in[6];
  const float* neg_vals   = (const float*)d_in[7];
  const int*   init_thax  = (const int*)d_in[8];
  const int*   init_sine  = (const int*)d_in[9];
  const int*   parents    = (const int*)d_in[10];
  const int*   rules      = (const int*)d_in[11];

  float* out = (float*)d_out;
  char* ws = (char*)d_ws;
  float* sums = (float*)ws;                       // ws+0
  unsigned* bvars = (unsigned*)(ws + 128);        // barrier cnt/gen
  unsigned* lvlcnt = (unsigned*)(ws + CNT_OFF);   // per-level counters
  unsigned short* store = (unsigned short*)(ws + ST_OFF);
  int* sorted_idx = (int*)(ws + SI_OFF);
  int* rule_off   = (int*)(ws + RO_OFF);

  (void)hipMemsetAsync(d_out, 0, 3 * sizeof(float), stream);
  (void)hipMemsetAsync(d_ws, 0, 1024, stream);  // sums + barrier + lvlcnt

  void* args[] = {&thax_table, &sine_table, &rule_W, &rule_b, &eval_w, &eval_b,
                  &pos_vals, &neg_vals, &init_thax, &init_sine, &parents,
                  &rules, &store, &sorted_idx, &rule_off, &lvlcnt, &sums,
                  &bvars, &out};
  (void)hipLaunchCooperativeKernel((void*)fused_kernel, dim3(NRULES),
                                   dim3(NTHR), args, 0, stream);
}

// Round 10
// 419.777 us; speedup vs baseline: 12.0606x; 12.0606x over previous
//
#include <hip/hip_runtime.h>

#define D      128
#define NINIT  100000
#define LVLS   64
#define M      4096
#define NRULES 256
#define NTOT   (NINIT + LVLS * M)
#define NTHR   512
#define TILE   32

typedef __attribute__((ext_vector_type(8))) short short8;   // 8 bf16 = 4 VGPRs
typedef __attribute__((ext_vector_type(4))) float floatx4;  // MFMA accumulator

// ---------------------------------------------------------------------------
// ws layout (bytes):
//   0      : sums[2] fp32
//   128    : barrier cnt (u32), barrier gen (u32)       (own cacheline)
//   256    : store  bf16 [NTOT][128]          (92,708,864 B)
//   SI_OFF : sorted_idx int [LVLS][M]          (1,048,576 B)
//   RO_OFF : rule_off  int [LVLS][NRULES+1]       (65,792 B)
//   FL_OFF : ready-flags u32 [LVLS*M]          (1,048,576 B)  (memset 0)
// Per-NODE flags (distributed over 1 MB -> bank-parallel polls). Round 9
// proved a centralized per-level counter livelocks under the poll storm.
// ---------------------------------------------------------------------------
#define ST_OFF 256
#define SI_OFF (ST_OFF + (size_t)NTOT * D * 2)
#define RO_OFF (SI_OFF + (size_t)LVLS * M * 4)
#define FL_OFF (RO_OFF + (size_t)LVLS * (NRULES + 1) * 4)

#define CBAR() asm volatile("" ::: "memory")

__device__ __forceinline__ unsigned short f2bf(float x) {  // RNE fp32->bf16
  unsigned u = __float_as_uint(x);
  u += 0x7fffu + ((u >> 16) & 1u);
  return (unsigned short)(u >> 16);
}

__device__ __forceinline__ float softplusf(float x) {
  return fmaxf(x, 0.f) + log1pf(expf(-fabsf(x)));
}

// --- LLC-coherent (cross-XCD) primitives. SYSTEM-scope relaxed atomics emit
// sc0 sc1 accesses: stores write through to the Infinity Cache (coherence
// point for all 8 XCDs), loads bypass L1/L2 and read it directly.
__device__ __forceinline__ void st_sys(unsigned* p, unsigned v) {
  __hip_atomic_store(p, v, __ATOMIC_RELAXED, __HIP_MEMORY_SCOPE_SYSTEM);
}
__device__ __forceinline__ void st_sys64(unsigned long long* p,
                                         unsigned long long v) {
  __hip_atomic_store(p, v, __ATOMIC_RELAXED, __HIP_MEMORY_SCOPE_SYSTEM);
}
__device__ __forceinline__ unsigned ld_sys(const unsigned* p) {
  return __hip_atomic_load(p, __ATOMIC_RELAXED, __HIP_MEMORY_SCOPE_SYSTEM);
}
// Spin with a cap: a protocol bug becomes a wrong answer, not a harness hang.
__device__ __forceinline__ void wait_flag(const unsigned* f) {
  int guard = 1 << 17;
  while (__builtin_expect(ld_sys(f) == 0u, 0) && --guard)
    __builtin_amdgcn_s_sleep(1);
  CBAR();
}

// Light grid barrier: fence-free. Valid because all cross-block data is
// written via st_sys (already at the LLC when __syncthreads drains vmcnt)
// and consumers never cached those lines beforehand. Used ONCE (after init).
__device__ __forceinline__ void gbar_light(unsigned* bcnt, unsigned* bgen) {
  __syncthreads();  // drains vmcnt: this block's sc-stores are at the LLC
  if (threadIdx.x == 0) {
    unsigned g = ld_sys(bgen);
    unsigned v = __hip_atomic_fetch_add(bcnt, 1u, __ATOMIC_RELAXED,
                                        __HIP_MEMORY_SCOPE_SYSTEM);
    if (v == gridDim.x - 1) {
      st_sys(bcnt, 0u);
      st_sys(bgen, g + 1u);
    } else {
      int guard = 1 << 22;
      while (ld_sys(bgen) == g && --guard) __builtin_amdgcn_s_sleep(2);
    }
  }
  __syncthreads();
}

// Cursor over rule r's 32-node tiles across all levels (skips empty levels).
__device__ __forceinline__ bool adv_cursor(int r, const int* __restrict__ ro,
                                           int& l, int& t0, int& off, int& cnt) {
  t0 += TILE;
  while (t0 >= cnt) {
    if (++l >= LVLS) return false;
    off = ro[l * (NRULES + 1) + r];
    cnt = ro[l * (NRULES + 1) + r + 1] - off;
    t0 = 0;
  }
  return true;
}

// One cooperative kernel. Block r owns rule r (B-fragments persistent in 32
// VGPRs). 32-node tiles, depth-3 pipeline, per-node LLC ready-flags
// (round-8 protocol, the best verified). New this round: INIT-node loss is
// computed inside phase A3 from the fp32 embeddings (pw-factored partials),
// deleting the 25.6 MB store re-read tail entirely.
__global__ __launch_bounds__(NTHR, 2) void fused_kernel(
    const float* __restrict__ thax_table, const float* __restrict__ sine_table,
    const float* __restrict__ rule_W, const float* __restrict__ rule_b,
    const float* __restrict__ eval_w, const float* __restrict__ eval_b,
    const float* __restrict__ pos, const float* __restrict__ neg,
    const int* __restrict__ init_thax, const int* __restrict__ init_sine,
    const int* __restrict__ parents,  // [LVLS][M][2]
    const int* __restrict__ rules,    // [LVLS][M]
    unsigned short* __restrict__ store, int* __restrict__ sorted_idx,
    int* __restrict__ rule_off, unsigned* __restrict__ flags,
    float* __restrict__ sums, unsigned* __restrict__ bvars,
    float* __restrict__ out) {
  __shared__ unsigned short pe[TILE * 264];  // gather tile: 32 x 256 + pad
  __shared__ unsigned short ot[TILE * 136];  // output tile: 32 x 128 + pad
  __shared__ int s_sid[2][TILE];
  __shared__ int s_cnt[NRULES];
  __shared__ int s_base[NRULES + 1];
  __shared__ float racc[4];

  unsigned* bcnt = bvars;
  unsigned* bgen = bvars + 1;

  const int r = blockIdx.x;
  const int tid = threadIdx.x;
  const int wave = tid >> 6, lane = tid & 63;
  const int col = (wave << 4) + (lane & 15);
  const int node = tid >> 4;   // 0..31: staged node
  const int segq = tid & 15;   // 16B chunk within each parent's 256B row
  const int gid = r * NTHR + tid;
  const int gthreads = NRULES * NTHR;

  // Loss accumulators, pw-factored: loss = pw*aP1 + aP2.
  float aP1 = 0.f, aP2 = 0.f, a_pos = 0.f, a_neg = 0.f;
  const float eb = eval_b[0];
  // Per-thread slice of eval_w (cols segq*8 .. segq*8+7). NOTE: in A3,
  // idx&15 == tid&15 == segq (gthreads and gid offsets are multiples of 16),
  // so this slice is valid for both the A3 init loss and the fused loop loss.
  float w8[8];
  {
    float4 wA = ((const float4*)eval_w)[segq * 2];
    float4 wB = ((const float4*)eval_w)[segq * 2 + 1];
    w8[0] = wA.x; w8[1] = wA.y; w8[2] = wA.z; w8[3] = wA.w;
    w8[4] = wB.x; w8[5] = wB.y; w8[6] = wB.z; w8[7] = wB.w;
  }

  // ---- Phase A1: rule-r weight fragments, fp32 global -> bf16 VGPRs (once).
  short8 bf[8];
  {
    const float* Wr = rule_W + (size_t)r * (2 * D * D);
    const int krow_base = (lane >> 4) * 8;
#pragma unroll
    for (int ks = 0; ks < 8; ++ks) {
      union { short8 s; unsigned short us[8]; } c;
#pragma unroll
      for (int j = 0; j < 8; ++j)
        c.us[j] = f2bf(Wr[(size_t)(ks * 32 + krow_base + j) * D + col]);
      bf[ks] = c.s;
    }
  }
  const float bias = rule_b[r * D + col];

  // ---- Phase A2: counting-sort nodes by rule (blocks 0..63, one level each).
  if (r < LVLS) {
    const int l = r;
    const int* rl = rules + (size_t)l * M;
    if (tid < NRULES) s_cnt[tid] = 0;
    __syncthreads();
    for (int m = tid; m < M; m += NTHR) atomicAdd(&s_cnt[rl[m]], 1);
    __syncthreads();
    if (tid == 0) {
      int run = 0;
      for (int q = 0; q < NRULES; ++q) { s_base[q] = run; run += s_cnt[q]; }
      s_base[NRULES] = run;
    }
    __syncthreads();
    if (tid < NRULES) {
      st_sys((unsigned*)&rule_off[(size_t)l * (NRULES + 1) + tid],
             (unsigned)s_base[tid]);
      s_cnt[tid] = s_base[tid];
    }
    if (tid == 0)
      st_sys((unsigned*)&rule_off[(size_t)l * (NRULES + 1) + NRULES],
             (unsigned)M);
    __syncthreads();
    for (int m = tid; m < M; m += NTHR) {
      int p = atomicAdd(&s_cnt[rl[m]], 1);
      st_sys((unsigned*)&sorted_idx[(size_t)l * M + p], (unsigned)m);
    }
  }

  // ---- Phase A3: init-node embeddings (sc-qwords) + FUSED init loss from
  // the fp32 values (16 consecutive lanes = one node; shfl tree reduces).
  for (int idx = gid; idx < NINIT * 16; idx += gthreads) {
    int nd = idx >> 4, sg = idx & 15;
    const float4* t = (const float4*)(thax_table + (size_t)init_thax[nd] * D) + sg * 2;
    const float4* s = (const float4*)(sine_table + (size_t)init_sine[nd] * D) + sg * 2;
    float4 a0 = t[0], a1 = t[1], b0 = s[0], b1 = s[1];
    float v[8] = {a0.x + b0.x, a0.y + b0.y, a0.z + b0.z, a0.w + b0.w,
                  a1.x + b1.x, a1.y + b1.y, a1.z + b1.z, a1.w + b1.w};
    unsigned p0 = (unsigned)f2bf(v[0]) | ((unsigned)f2bf(v[1]) << 16);
    unsigned p1 = (unsigned)f2bf(v[2]) | ((unsigned)f2bf(v[3]) << 16);
    unsigned p2 = (unsigned)f2bf(v[4]) | ((unsigned)f2bf(v[5]) << 16);
    unsigned p3 = (unsigned)f2bf(v[6]) | ((unsigned)f2bf(v[7]) << 16);
    unsigned long long* dst =
        (unsigned long long*)(store + (size_t)nd * D + sg * 8);
    st_sys64(dst + 0, (unsigned long long)p0 | ((unsigned long long)p1 << 32));
    st_sys64(dst + 1, (unsigned long long)p2 | ((unsigned long long)p3 << 32));

    float pd = v[0] * w8[0] + v[1] * w8[1] + v[2] * w8[2] + v[3] * w8[3] +
               v[4] * w8[4] + v[5] * w8[5] + v[6] * w8[6] + v[7] * w8[7];
    pd += __shfl_xor(pd, 1, 64);
    pd += __shfl_xor(pd, 2, 64);
    pd += __shfl_xor(pd, 4, 64);
    pd += __shfl_xor(pd, 8, 64);
    if (sg == 0) {
      float logit = pd + eb;
      float pp = pos[nd], nn = neg[nd];
      float tot = pp + nn, y = pp / tot;
      aP1 += tot * y * softplusf(-logit);
      aP2 += tot * (1.f - y) * softplusf(logit);
      if (logit >= 0.f) a_pos += pp; else a_neg += nn;
    }
  }

  // ---- Phase A4: pos/neg sums.
  {
    float sp = 0.f, sn = 0.f;
    for (int i = gid; i < NTOT; i += gthreads) {
      sp += pos[i];
      sn += neg[i];
    }
    for (int m = 32; m; m >>= 1) {
      sp += __shfl_xor(sp, m, 64);
      sn += __shfl_xor(sn, m, 64);
    }
    if (lane == 0) {
      atomicAdd(&sums[0], sp);
      atomicAdd(&sums[1], sn);
    }
  }

  gbar_light(bcnt, bgen);  // publish sort/init/sums (all sc-written)

  const float pw = sums[1] / sums[0];  // valid after the barrier

  // ---- Level loop: depth-3 tile pipeline (A=compute, B=rows, C=flags,
  // D=idx), per-node flags, no grid barriers. (Round-8 protocol verbatim.)
  int lL = -1, t0L = 0, offL = 0, cntL = 0;

  bool validA = adv_cursor(r, rule_off, lL, t0L, offL, cntL);
  int lA = lL, t0A = t0L, cntA = cntL;
  int parA0 = 0, parA1 = 0;
  bool lateA0 = false, lateA1 = false;
  unsigned reA0 = 1u, reA1 = 1u;
  float pPosA = 0.f, pNegA = 0.f;
  uint4 gA0 = {0, 0, 0, 0}, gA1 = {0, 0, 0, 0};
  if (validA) {
    int gj = t0A + node; if (gj > cntA - 1) gj = cntA - 1;
    int sid = sorted_idx[(size_t)lA * M + offL + gj];
    parA0 = parents[((size_t)lA * M + sid) * 2 + 0];
    parA1 = parents[((size_t)lA * M + sid) * 2 + 1];
    pPosA = pos[NINIT + lA * M + sid];
    pNegA = neg[NINIT + lA * M + sid];
    if (parA0 >= NINIT) wait_flag(flags + (parA0 - NINIT));
    if (parA1 >= NINIT) wait_flag(flags + (parA1 - NINIT));
    gA0 = *(const uint4*)(store + (size_t)parA0 * D + segq * 8);
    gA1 = *(const uint4*)(store + (size_t)parA1 * D + segq * 8);
    if (segq == 0) s_sid[0][node] = sid;
  }

  bool validB = validA && adv_cursor(r, rule_off, lL, t0L, offL, cntL);
  int lB = lL, t0B = t0L, cntB = cntL;
  int sidB = 0, parB0 = 0, parB1 = 0;
  unsigned fB0 = 1u, fB1 = 1u;
  if (validB) {
    int gj = t0B + node; if (gj > cntB - 1) gj = cntB - 1;
    sidB = sorted_idx[(size_t)lB * M + offL + gj];
    parB0 = parents[((size_t)lB * M + sidB) * 2 + 0];
    parB1 = parents[((size_t)lB * M + sidB) * 2 + 1];
    fB0 = parB0 >= NINIT ? ld_sys(flags + (parB0 - NINIT)) : 1u;
    fB1 = parB1 >= NINIT ? ld_sys(flags + (parB1 - NINIT)) : 1u;
  }

  bool validC = validB && adv_cursor(r, rule_off, lL, t0L, offL, cntL);
  int lC = lL, t0C = t0L, cntC = cntL;
  int sidC = 0, parC0 = 0, parC1 = 0;
  if (validC) {
    int gj = t0C + node; if (gj > cntC - 1) gj = cntC - 1;
    sidC = sorted_idx[(size_t)lC * M + offL + gj];
    parC0 = parents[((size_t)lC * M + sidC) * 2 + 0];
    parC1 = parents[((size_t)lC * M + sidC) * 2 + 1];
  }

  bool validD = validC && adv_cursor(r, rule_off, lL, t0L, offL, cntL);
  int lD = lL, t0D = t0L, offD = offL, cntD = cntL;

  int p = 0;
  while (validA) {
    // (0) late-resolve A: combined spin over both parents (one poll RT),
    // skipped when the end-of-iteration re-poll already saw the flags.
    if (lateA0 || lateA1) {
      bool n0 = lateA0 && (reA0 == 0u);
      bool n1 = lateA1 && (reA1 == 0u);
      if (n0 || n1) {
        int guard = 1 << 17;
        while (guard--) {
          unsigned f0 = n0 ? ld_sys(flags + (parA0 - NINIT)) : 1u;
          unsigned f1 = n1 ? ld_sys(flags + (parA1 - NINIT)) : 1u;
          if (f0 != 0u && f1 != 0u) break;
          __builtin_amdgcn_s_sleep(1);
        }
      }
      CBAR();
      if (lateA0) gA0 = *(const uint4*)(store + (size_t)parA0 * D + segq * 8);
      if (lateA1) gA1 = *(const uint4*)(store + (size_t)parA1 * D + segq * 8);
    }

    // (1) stage pe
    *(uint4*)(pe + node * 264 + segq * 8) = gA0;
    *(uint4*)(pe + node * 264 + 128 + segq * 8) = gA1;
    __syncthreads();
    if (validB && segq == 0) s_sid[p ^ 1][node] = sidB;

    // (2) 16 MFMA (two 16-node halves) + ReLU/bias -> transpose tile
    floatx4 acc0 = {0.f, 0.f, 0.f, 0.f}, acc1 = {0.f, 0.f, 0.f, 0.f};
#pragma unroll
    for (int ks = 0; ks < 8; ++ks) {
      short8 a0 = *(const short8*)(pe + (lane & 15) * 264 + ks * 32 + (lane >> 4) * 8);
      short8 a1 = *(const short8*)(pe + (16 + (lane & 15)) * 264 + ks * 32 + (lane >> 4) * 8);
      acc0 = __builtin_amdgcn_mfma_f32_16x16x32_bf16(a0, bf[ks], acc0, 0, 0, 0);
      acc1 = __builtin_amdgcn_mfma_f32_16x16x32_bf16(a1, bf[ks], acc1, 0, 0, 0);
    }
#pragma unroll
    for (int reg = 0; reg < 4; ++reg) {
      int row = (lane >> 4) * 4 + reg;
      float v0 = acc0[reg] + bias;
      float v1 = acc1[reg] + bias;
      ot[row * 136 + col] = f2bf(v0 > 0.f ? v0 : 0.f);
      ot[(16 + row) * 136 + col] = f2bf(v1 > 0.f ? v1 : 0.f);
    }
    __syncthreads();

    // (3) rows(A) + staggered flag publication. Wave w owns nodes
    // {w,w+8,w+16,w+24}. Stores retire in issue order; each flag store
    // also increments vmcnt, so row k is at the LLC before flag k goes.
    {
      const int n_baseA = NINIT + lA * M;
      int nsid[4]; bool inr[4]; int S = 0;
#pragma unroll
      for (int k = 0; k < 4; ++k) {
        int nd = wave + 8 * k;
        nsid[k] = s_sid[p][nd];
        inr[k] = (t0A + nd) < cntA;  // wave-uniform
        if (inr[k]) {
          st_sys((unsigned*)(store + (size_t)(n_baseA + nsid[k]) * D) + lane,
                 *(const unsigned*)(ot + nd * 136 + lane * 2));
          ++S;
        }
      }
      CBAR();
#pragma unroll
      for (int k = 0; k < 4; ++k) {
        if (inr[k]) {
          if (S == 4)      asm volatile("s_waitcnt vmcnt(3)" ::: "memory");
          else if (S == 3) asm volatile("s_waitcnt vmcnt(2)" ::: "memory");
          else if (S == 2) asm volatile("s_waitcnt vmcnt(1)" ::: "memory");
          else             asm volatile("s_waitcnt vmcnt(0)" ::: "memory");
          if (lane == 0) st_sys(flags + lA * M + nsid[k], 1u);
        }
      }
      CBAR();  // flags issued before any later spin
    }

    // (4) prefetches. Gathers(B) first; unready lanes read a dummy (row 0)
    // address so no stale line is ever cached.
    bool lateB0 = validB && parB0 >= NINIT && fB0 == 0u;
    bool lateB1 = validB && parB1 >= NINIT && fB1 == 0u;
    uint4 gB0, gB1;
    {
      const unsigned short* a0 =
          (validB && !lateB0) ? store + (size_t)parB0 * D : store;
      const unsigned short* a1 =
          (validB && !lateB1) ? store + (size_t)parB1 * D : store;
      gB0 = *(const uint4*)(a0 + segq * 8);
      gB1 = *(const uint4*)(a1 + segq * 8);
    }
    float pPosB = 0.f, pNegB = 0.f;
    if (validB) {
      pPosB = pos[NINIT + lB * M + sidB];
      pNegB = neg[NINIT + lB * M + sidB];
    }
    int sidD = 0, parD0 = 0, parD1 = 0;
    if (validD) {
      int gj = t0D + node; if (gj > cntD - 1) gj = cntD - 1;
      sidD = sorted_idx[(size_t)lD * M + offD + gj];
      parD0 = parents[((size_t)lD * M + sidD) * 2 + 0];
      parD1 = parents[((size_t)lD * M + sidD) * 2 + 1];
    }
    unsigned fC0 = 1u, fC1 = 1u;
    if (validC) {
      fC0 = ld_sys(flags + (parC0 >= NINIT ? parC0 - NINIT : 0));
      fC1 = ld_sys(flags + (parC1 >= NINIT ? parC1 - NINIT : 0));
      if (parC0 < NINIT) fC0 = 1u;
      if (parC1 < NINIT) fC1 = 1u;
    }
    // End re-poll of late B-parents (producers publish around now).
    unsigned reB0 = 1u, reB1 = 1u;
    if (lateB0) reB0 = ld_sys(flags + (parB0 - NINIT));
    if (lateB1) reB1 = ld_sys(flags + (parB1 - NINIT));
    CBAR();

    // (L) fused derived-node loss from the ot tile (pure VALU; hides under
    // the outstanding prefetch latency).
    {
      const uint4 u = *(const uint4*)(ot + node * 136 + segq * 8);
      float pd = __uint_as_float(u.x << 16) * w8[0] +
                 __uint_as_float(u.x & 0xffff0000u) * w8[1] +
                 __uint_as_float(u.y << 16) * w8[2] +
                 __uint_as_float(u.y & 0xffff0000u) * w8[3] +
                 __uint_as_float(u.z << 16) * w8[4] +
                 __uint_as_float(u.z & 0xffff0000u) * w8[5] +
                 __uint_as_float(u.w << 16) * w8[6] +
                 __uint_as_float(u.w & 0xffff0000u) * w8[7];
      pd += __shfl_xor(pd, 1, 64);
      pd += __shfl_xor(pd, 2, 64);
      pd += __shfl_xor(pd, 4, 64);
      pd += __shfl_xor(pd, 8, 64);
      if (segq == 0 && (t0A + node) < cntA) {
        float logit = pd + eb;
        float tot = pPosA + pNegA, y = pPosA / tot;
        aP1 += tot * y * softplusf(-logit);
        aP2 += tot * (1.f - y) * softplusf(logit);
        if (logit >= 0.f) a_pos += pPosA; else a_neg += pNegA;
      }
    }

    // (5) shift pipeline slots
    gA0 = gB0; gA1 = gB1; lateA0 = lateB0; lateA1 = lateB1;
    reA0 = reB0; reA1 = reB1;
    parA0 = parB0; parA1 = parB1;
    pPosA = pPosB; pNegA = pNegB;
    lA = lB; t0A = t0B; cntA = cntB; validA = validB;
    sidB = sidC; parB0 = parC0; parB1 = parC1; fB0 = fC0; fB1 = fC1;
    lB = lC; t0B = t0C; cntB = cntC; validB = validC;
    sidC = sidD; parC0 = parD0; parC1 = parD1;
    lC = lD; t0C = t0D; cntC = cntD; validC = validD;
    validD = validC && adv_cursor(r, rule_off, lL, t0L, offL, cntL);
    lD = lL; t0D = t0L; offD = offL; cntD = cntL;
    p ^= 1;
  }

  // ---- Final reduction: wave shfl -> block LDS -> device atomics.
  // (No init tail: init loss was fused into A3.)
  for (int m = 32; m; m >>= 1) {
    aP1   += __shfl_xor(aP1,   m, 64);
    aP2   += __shfl_xor(aP2,   m, 64);
    a_pos += __shfl_xor(a_pos, m, 64);
    a_neg += __shfl_xor(a_neg, m, 64);
  }
  if (tid == 0) { racc[0] = 0.f; racc[1] = 0.f; racc[2] = 0.f; racc[3] = 0.f; }
  __syncthreads();
  if (lane == 0) {
    atomicAdd(&racc[0], aP1);
    atomicAdd(&racc[1], aP2);
    atomicAdd(&racc[2], a_pos);
    atomicAdd(&racc[3], a_neg);
  }
  __syncthreads();
  if (tid == 0) {
    atomicAdd(&out[0], pw * racc[0] + racc[1]);
    atomicAdd(&out[1], racc[2]);
    atomicAdd(&out[2], racc[3]);
  }
}

extern "C" void kernel_launch(void* const* d_in, const int* in_sizes, int n_in,
                              void* d_out, int out_size, void* d_ws, size_t ws_size,
                              hipStream_t stream) {
  const float* thax_table = (const float*)d_in[0];
  const float* sine_table = (const float*)d_in[1];
  const float* rule_W     = (const float*)d_in[2];
  const float* rule_b     = (const float*)d_in[3];
  const float* eval_w     = (const float*)d_in[4];
  const float* eval_b     = (const float*)d_in[5];
  const float* pos_vals   = (const float*)d_in[6];
  const float* neg_vals   = (const float*)d_in[7];
  const int*   init_thax  = (const int*)d_in[8];
  const int*   init_sine  = (const int*)d_in[9];
  const int*   parents    = (const int*)d_in[10];
  const int*   rules      = (const int*)d_in[11];

  float* out = (float*)d_out;
  char* ws = (char*)d_ws;
  float* sums = (float*)ws;                       // ws+0
  unsigned* bvars = (unsigned*)(ws + 128);        // barrier cnt/gen
  unsigned short* store = (unsigned short*)(ws + ST_OFF);
  int* sorted_idx = (int*)(ws + SI_OFF);
  int* rule_off   = (int*)(ws + RO_OFF);
  unsigned* flags = (unsigned*)(ws + FL_OFF);

  (void)hipMemsetAsync(d_out, 0, 3 * sizeof(float), stream);
  (void)hipMemsetAsync(d_ws, 0, 256, stream);                         // sums+bar
  (void)hipMemsetAsync(ws + FL_OFF, 0, (size_t)LVLS * M * 4, stream); // flags

  void* args[] = {&thax_table, &sine_table, &rule_W, &rule_b, &eval_w, &eval_b,
                  &pos_vals, &neg_vals, &init_thax, &init_sine, &parents,
                  &rules, &store, &sorted_idx, &rule_off, &flags, &sums,
                  &bvars, &out};
  (void)hipLaunchCooperativeKernel((void*)fused_kernel, dim3(NRULES),
                                   dim3(NTHR), args, 0, stream);
}

// Round 11
// 389.577 us; speedup vs baseline: 12.9955x; 1.0775x over previous
//
#include <hip/hip_runtime.h>

#define D      128
#define NINIT  100000
#define LVLS   64
#define M      4096
#define NRULES 256
#define NTOT   (NINIT + LVLS * M)
#define NTHR   512
#define TILE   32

typedef __attribute__((ext_vector_type(8))) short short8;   // 8 bf16 = 4 VGPRs
typedef __attribute__((ext_vector_type(4))) float floatx4;  // MFMA accumulator

// ---------------------------------------------------------------------------
// ws layout (bytes):
//   0      : sums[2] fp32
//   128    : barrier cnt (u32), barrier gen (u32)       (own cacheline)
//   256    : store  bf16 [NTOT][128]          (92,708,864 B)
//   SI_OFF : sorted_idx int [LVLS][M]          (1,048,576 B)
//   RO_OFF : rule_off  int [LVLS][NRULES+1]       (65,792 B)
//   FL_OFF : ready-flags u32 [LVLS*M]          (1,048,576 B)  (memset 0)
// Per-NODE flags distributed over 1 MB (bank-parallel). Round 9 proved a
// centralized per-level counter livelocks under the poll storm.
// ---------------------------------------------------------------------------
#define ST_OFF 256
#define SI_OFF (ST_OFF + (size_t)NTOT * D * 2)
#define RO_OFF (SI_OFF + (size_t)LVLS * M * 4)
#define FL_OFF (RO_OFF + (size_t)LVLS * (NRULES + 1) * 4)

#define CBAR() asm volatile("" ::: "memory")

__device__ __forceinline__ unsigned short f2bf(float x) {  // RNE fp32->bf16
  unsigned u = __float_as_uint(x);
  u += 0x7fffu + ((u >> 16) & 1u);
  return (unsigned short)(u >> 16);
}

__device__ __forceinline__ float softplusf(float x) {
  return fmaxf(x, 0.f) + log1pf(expf(-fabsf(x)));
}

// --- LLC-coherent (cross-XCD) primitives (sc0 sc1 accesses).
__device__ __forceinline__ void st_sys(unsigned* p, unsigned v) {
  __hip_atomic_store(p, v, __ATOMIC_RELAXED, __HIP_MEMORY_SCOPE_SYSTEM);
}
__device__ __forceinline__ void st_sys64(unsigned long long* p,
                                         unsigned long long v) {
  __hip_atomic_store(p, v, __ATOMIC_RELAXED, __HIP_MEMORY_SCOPE_SYSTEM);
}
__device__ __forceinline__ unsigned ld_sys(const unsigned* p) {
  return __hip_atomic_load(p, __ATOMIC_RELAXED, __HIP_MEMORY_SCOPE_SYSTEM);
}

// Dual-flag spin with 2-deep pipelined polling: check poll k while poll k+1
// is in flight -> discovery period ~RT/2 instead of ~RT. Capped (a protocol
// bug becomes a wrong answer, not a hang).
__device__ __forceinline__ void wait2(const unsigned* f0, bool n0,
                                      const unsigned* f1, bool n1) {
  if (__all(!(n0 || n1))) return;
  unsigned a0 = ld_sys(f0), a1 = ld_sys(f1);
  int guard = 1 << 16;
  for (;;) {
    unsigned b0 = ld_sys(f0), b1 = ld_sys(f1);
    bool ok = (!n0 || a0 != 0u) && (!n1 || a1 != 0u);
    if (__all(ok) || !--guard) break;
    a0 = ld_sys(f0); a1 = ld_sys(f1);
    ok = (!n0 || b0 != 0u) && (!n1 || b1 != 0u);
    if (__all(ok) || !--guard) break;
  }
  CBAR();
}

// Light grid barrier: fence-free (all cross-block data is sc-written; the
// __syncthreads vmcnt-drain puts it at the LLC). Used ONCE, after init.
__device__ __forceinline__ void gbar_light(unsigned* bcnt, unsigned* bgen) {
  __syncthreads();
  if (threadIdx.x == 0) {
    unsigned g = ld_sys(bgen);
    unsigned v = __hip_atomic_fetch_add(bcnt, 1u, __ATOMIC_RELAXED,
                                        __HIP_MEMORY_SCOPE_SYSTEM);
    if (v == gridDim.x - 1) {
      st_sys(bcnt, 0u);
      st_sys(bgen, g + 1u);
    } else {
      int guard = 1 << 22;
      while (ld_sys(bgen) == g && --guard) __builtin_amdgcn_s_sleep(2);
    }
  }
  __syncthreads();
}

// Cursor over rule r's 32-node tiles across all levels (skips empty levels).
__device__ __forceinline__ bool adv_cursor(int r, const int* __restrict__ ro,
                                           int& l, int& t0, int& off, int& cnt) {
  t0 += TILE;
  while (t0 >= cnt) {
    if (++l >= LVLS) return false;
    off = ro[l * (NRULES + 1) + r];
    cnt = ro[l * (NRULES + 1) + r + 1] - off;
    t0 = 0;
  }
  return true;
}

// One cooperative kernel. Block r owns rule r (B-fragments persistent in 32
// VGPRs). 32-node tiles; DEPTH-5 pipeline (A=compute, B=gathered, C=polled,
// E=par-fetched, F=sid-fetched) so all 10 prefetch loads per iteration are
// independent; 2-deep pipelined flag spins; single counted drain + single
// scatter flag publication.
__global__ __launch_bounds__(NTHR, 2) void fused_kernel(
    const float* __restrict__ thax_table, const float* __restrict__ sine_table,
    const float* __restrict__ rule_W, const float* __restrict__ rule_b,
    const float* __restrict__ eval_w, const float* __restrict__ eval_b,
    const float* __restrict__ pos, const float* __restrict__ neg,
    const int* __restrict__ init_thax, const int* __restrict__ init_sine,
    const int* __restrict__ parents,  // [LVLS][M][2]
    const int* __restrict__ rules,    // [LVLS][M]
    unsigned short* __restrict__ store, int* __restrict__ sorted_idx,
    int* __restrict__ rule_off, unsigned* __restrict__ flags,
    float* __restrict__ sums, unsigned* __restrict__ bvars,
    float* __restrict__ out) {
  __shared__ unsigned short pe[TILE * 264];  // gather tile: 32 x 512B + pad
  __shared__ unsigned short ot[TILE * 136];  // output tile: 32 x 256B + pad
  __shared__ int s_sid[2][TILE];
  __shared__ int s_cnt[NRULES];
  __shared__ int s_base[NRULES + 1];
  __shared__ float racc[4];

  unsigned* bcnt = bvars;
  unsigned* bgen = bvars + 1;

  const int r = blockIdx.x;
  const int tid = threadIdx.x;
  const int wave = tid >> 6, lane = tid & 63;
  const int col = (wave << 4) + (lane & 15);
  const int node = tid >> 4;   // 0..31: staged node
  const int segq = tid & 15;   // 16B chunk within each parent's 256B row

  // Loss accumulators, pw-factored: loss = pw*aP1 + aP2.
  float aP1 = 0.f, aP2 = 0.f, a_pos = 0.f, a_neg = 0.f;
  const float eb = eval_b[0];
  float w8[8];
  {
    float4 wA = ((const float4*)eval_w)[segq * 2];
    float4 wB = ((const float4*)eval_w)[segq * 2 + 1];
    w8[0] = wA.x; w8[1] = wA.y; w8[2] = wA.z; w8[3] = wA.w;
    w8[4] = wB.x; w8[5] = wB.y; w8[6] = wB.z; w8[7] = wB.w;
  }

  // ---- Phase A1: rule-r weight fragments, fp32 global -> bf16 VGPRs (once).
  short8 bf[8];
  {
    const float* Wr = rule_W + (size_t)r * (2 * D * D);
    const int krow_base = (lane >> 4) * 8;
#pragma unroll
    for (int ks = 0; ks < 8; ++ks) {
      union { short8 s; unsigned short us[8]; } c;
#pragma unroll
      for (int j = 0; j < 8; ++j)
        c.us[j] = f2bf(Wr[(size_t)(ks * 32 + krow_base + j) * D + col]);
      bf[ks] = c.s;
    }
  }
  const float bias = rule_b[r * D + col];

  if (r < LVLS) {
    // ---- Phase A2 (blocks 0..63 ONLY): counting-sort one level by rule,
    // with a parallel Kogge-Stone prefix scan (no serial 256-loop).
    const int l = r;
    const int* rl = rules + (size_t)l * M;
    if (tid < NRULES) s_cnt[tid] = 0;
    __syncthreads();
    for (int m = tid; m < M; m += NTHR) atomicAdd(&s_cnt[rl[m]], 1);
    __syncthreads();
    int c = (tid < NRULES) ? s_cnt[tid] : 0;
    if (tid < NRULES) s_base[tid] = c;
    __syncthreads();
    for (int off = 1; off < NRULES; off <<= 1) {
      int t = (tid < NRULES && tid >= off) ? s_base[tid - off] : 0;
      __syncthreads();
      if (tid < NRULES) s_base[tid] += t;
      __syncthreads();
    }
    if (tid < NRULES) {
      int ex = s_base[tid] - c;  // exclusive prefix
      st_sys((unsigned*)&rule_off[(size_t)l * (NRULES + 1) + tid],
             (unsigned)ex);
      s_cnt[tid] = ex;
    }
    if (tid == 0)
      st_sys((unsigned*)&rule_off[(size_t)l * (NRULES + 1) + NRULES],
             (unsigned)M);
    __syncthreads();
    for (int m = tid; m < M; m += NTHR) {
      int p = atomicAdd(&s_cnt[rl[m]], 1);
      st_sys((unsigned*)&sorted_idx[(size_t)l * M + p], (unsigned)m);
    }
  } else {
    // ---- Phase A3 (blocks 64..255): init embeddings + fused init loss.
    const int gid3 = (r - LVLS) * NTHR + tid;
    const int gstride3 = (NRULES - LVLS) * NTHR;
    for (int idx = gid3; idx < NINIT * 16; idx += gstride3) {
      int nd = idx >> 4, sg = idx & 15;  // sg == segq (stride mult of 16)
      const float4* t = (const float4*)(thax_table + (size_t)init_thax[nd] * D) + sg * 2;
      const float4* s = (const float4*)(sine_table + (size_t)init_sine[nd] * D) + sg * 2;
      float4 a0 = t[0], a1 = t[1], b0 = s[0], b1 = s[1];
      float v[8] = {a0.x + b0.x, a0.y + b0.y, a0.z + b0.z, a0.w + b0.w,
                    a1.x + b1.x, a1.y + b1.y, a1.z + b1.z, a1.w + b1.w};
      unsigned p0 = (unsigned)f2bf(v[0]) | ((unsigned)f2bf(v[1]) << 16);
      unsigned p1 = (unsigned)f2bf(v[2]) | ((unsigned)f2bf(v[3]) << 16);
      unsigned p2 = (unsigned)f2bf(v[4]) | ((unsigned)f2bf(v[5]) << 16);
      unsigned p3 = (unsigned)f2bf(v[6]) | ((unsigned)f2bf(v[7]) << 16);
      unsigned long long* dst =
          (unsigned long long*)(store + (size_t)nd * D + sg * 8);
      st_sys64(dst + 0, (unsigned long long)p0 | ((unsigned long long)p1 << 32));
      st_sys64(dst + 1, (unsigned long long)p2 | ((unsigned long long)p3 << 32));

      float pd = v[0] * w8[0] + v[1] * w8[1] + v[2] * w8[2] + v[3] * w8[3] +
                 v[4] * w8[4] + v[5] * w8[5] + v[6] * w8[6] + v[7] * w8[7];
      pd += __shfl_xor(pd, 1, 64);
      pd += __shfl_xor(pd, 2, 64);
      pd += __shfl_xor(pd, 4, 64);
      pd += __shfl_xor(pd, 8, 64);
      if (sg == 0) {
        float logit = pd + eb;
        float pp = pos[nd], nn = neg[nd];
        float tot = pp + nn, y = pp / tot;
        aP1 += tot * y * softplusf(-logit);
        aP2 += tot * (1.f - y) * softplusf(logit);
        if (logit >= 0.f) a_pos += pp; else a_neg += nn;
      }
    }
    // ---- Phase A4 (blocks 64..255): pos/neg sums.
    float sp = 0.f, sn = 0.f;
    for (int i = gid3; i < NTOT; i += gstride3) {
      sp += pos[i];
      sn += neg[i];
    }
    for (int m = 32; m; m >>= 1) {
      sp += __shfl_xor(sp, m, 64);
      sn += __shfl_xor(sn, m, 64);
    }
    if (lane == 0) {
      atomicAdd(&sums[0], sp);
      atomicAdd(&sums[1], sn);
    }
  }

  gbar_light(bcnt, bgen);  // publish sort/init/sums (all sc-written)

  const float pw = sums[1] / sums[0];  // valid after the barrier

  // ---- Depth-5 pipeline prime ------------------------------------------
  int lL = -1, t0L = 0, offL = 0, cntL = 0;

  // Slot A (compute next)
  bool validA = adv_cursor(r, rule_off, lL, t0L, offL, cntL);
  int lA = lL, t0A = t0L, cntA = cntL;
  int parA0 = 0, parA1 = 0;
  bool lateA0 = false, lateA1 = false;
  unsigned reA0 = 1u, reA1 = 1u;
  float pPosA = 0.f, pNegA = 0.f;
  uint4 gA0 = {0, 0, 0, 0}, gA1 = {0, 0, 0, 0};
  if (validA) {
    int gj = t0A + node; if (gj > cntA - 1) gj = cntA - 1;
    int sid = sorted_idx[(size_t)lA * M + offL + gj];
    parA0 = parents[((size_t)lA * M + sid) * 2 + 0];
    parA1 = parents[((size_t)lA * M + sid) * 2 + 1];
    pPosA = pos[NINIT + lA * M + sid];
    pNegA = neg[NINIT + lA * M + sid];
    bool n0 = parA0 >= NINIT, n1 = parA1 >= NINIT;
    wait2(flags + (n0 ? parA0 - NINIT : 0), n0,
          flags + (n1 ? parA1 - NINIT : 0), n1);
    gA0 = *(const uint4*)(store + (size_t)parA0 * D + segq * 8);
    gA1 = *(const uint4*)(store + (size_t)parA1 * D + segq * 8);
    if (segq == 0) s_sid[0][node] = sid;
  }

  // Slot B (gather next)
  bool validB = validA && adv_cursor(r, rule_off, lL, t0L, offL, cntL);
  int lB = lL, t0B = t0L, cntB = cntL;
  int sidB = 0, parB0 = 0, parB1 = 0;
  unsigned fB0 = 1u, fB1 = 1u;
  float pPosB = 0.f, pNegB = 0.f;
  if (validB) {
    int gj = t0B + node; if (gj > cntB - 1) gj = cntB - 1;
    sidB = sorted_idx[(size_t)lB * M + offL + gj];
    parB0 = parents[((size_t)lB * M + sidB) * 2 + 0];
    parB1 = parents[((size_t)lB * M + sidB) * 2 + 1];
    fB0 = parB0 >= NINIT ? ld_sys(flags + (parB0 - NINIT)) : 1u;
    fB1 = parB1 >= NINIT ? ld_sys(flags + (parB1 - NINIT)) : 1u;
    pPosB = pos[NINIT + lB * M + sidB];
    pNegB = neg[NINIT + lB * M + sidB];
  }

  // Slot C (flag-poll next)
  bool validC = validB && adv_cursor(r, rule_off, lL, t0L, offL, cntL);
  int lC = lL, t0C = t0L, cntC = cntL;
  int sidC = 0, parC0 = 0, parC1 = 0;
  if (validC) {
    int gj = t0C + node; if (gj > cntC - 1) gj = cntC - 1;
    sidC = sorted_idx[(size_t)lC * M + offL + gj];
    parC0 = parents[((size_t)lC * M + sidC) * 2 + 0];
    parC1 = parents[((size_t)lC * M + sidC) * 2 + 1];
  }

  // Slot E (par-fetch next)
  bool validE = validC && adv_cursor(r, rule_off, lL, t0L, offL, cntL);
  int lE = lL, t0E = t0L, cntE = cntL;
  int sidE = 0;
  if (validE) {
    int gj = t0E + node; if (gj > cntE - 1) gj = cntE - 1;
    sidE = sorted_idx[(size_t)lE * M + offL + gj];
  }

  // Slot F (sid-fetch next) = cursor position
  bool validF = validE && adv_cursor(r, rule_off, lL, t0L, offL, cntL);
  int lF = lL, t0F = t0L, offF = offL, cntF = cntL;

  int p = 0;
  while (validA) {
    // (0) late-resolve A: pipelined dual spin; skip if end-re-poll saw them.
    {
      bool n0 = lateA0 && (reA0 == 0u);
      bool n1 = lateA1 && (reA1 == 0u);
      wait2(flags + (lateA0 ? parA0 - NINIT : 0), n0,
            flags + (lateA1 ? parA1 - NINIT : 0), n1);
      if (lateA0) gA0 = *(const uint4*)(store + (size_t)parA0 * D + segq * 8);
      if (lateA1) gA1 = *(const uint4*)(store + (size_t)parA1 * D + segq * 8);
    }

    // (1) stage pe
    *(uint4*)(pe + node * 264 + segq * 8) = gA0;
    *(uint4*)(pe + node * 264 + 128 + segq * 8) = gA1;
    __syncthreads();
    if (validB && segq == 0) s_sid[p ^ 1][node] = sidB;

    // (2) 16 MFMA + ReLU/bias -> transpose tile
    floatx4 acc0 = {0.f, 0.f, 0.f, 0.f}, acc1 = {0.f, 0.f, 0.f, 0.f};
#pragma unroll
    for (int ks = 0; ks < 8; ++ks) {
      short8 a0 = *(const short8*)(pe + (lane & 15) * 264 + ks * 32 + (lane >> 4) * 8);
      short8 a1 = *(const short8*)(pe + (16 + (lane & 15)) * 264 + ks * 32 + (lane >> 4) * 8);
      acc0 = __builtin_amdgcn_mfma_f32_16x16x32_bf16(a0, bf[ks], acc0, 0, 0, 0);
      acc1 = __builtin_amdgcn_mfma_f32_16x16x32_bf16(a1, bf[ks], acc1, 0, 0, 0);
    }
#pragma unroll
    for (int reg = 0; reg < 4; ++reg) {
      int row = (lane >> 4) * 4 + reg;
      float v0 = acc0[reg] + bias;
      float v1 = acc1[reg] + bias;
      ot[row * 136 + col] = f2bf(v0 > 0.f ? v0 : 0.f);
      ot[(16 + row) * 136 + col] = f2bf(v1 > 0.f ? v1 : 0.f);
    }
    __syncthreads();

    // (3) rows(A): wave w owns nodes {w,w+8,w+16,w+24} (wave-uniform conds).
    const int n_baseA = NINIT + lA * M;
#pragma unroll
    for (int k = 0; k < 4; ++k) {
      int nd = wave + 8 * k;
      if ((t0A + nd) < cntA)
        st_sys((unsigned*)(store + (size_t)(n_baseA + s_sid[p][nd]) * D) + lane,
               *(const unsigned*)(ot + nd * 136 + lane * 2));
    }
    CBAR();  // prefetches stay AFTER the row stores in issue order

    // (4) EXACTLY 10 independent uniform loads (clamped dummy addresses for
    // invalid slots / unready lanes -> no stale line is ever cached).
    bool lateB0 = validB && parB0 >= NINIT && fB0 == 0u;
    bool lateB1 = validB && parB1 >= NINIT && fB1 == 0u;
    const unsigned short* ga0 =
        (validB && !lateB0) ? store + (size_t)parB0 * D : store;
    const unsigned short* ga1 =
        (validB && !lateB1) ? store + (size_t)parB1 * D : store;
    uint4 gB0 = *(const uint4*)(ga0 + segq * 8);                       // 1
    uint4 gB1 = *(const uint4*)(ga1 + segq * 8);                       // 2
    unsigned pol0 =
        ld_sys(flags + ((validC && parC0 >= NINIT) ? parC0 - NINIT : 0)); // 3
    unsigned pol1 =
        ld_sys(flags + ((validC && parC1 >= NINIT) ? parC1 - NINIT : 0)); // 4
    int idxC = NINIT + lC * M + sidC;
    float posC = pos[validC ? idxC : 0];                               // 5
    float negC = neg[validC ? idxC : 0];                               // 6
    int2 prE = *(const int2*)(parents +
                (validE ? (((size_t)lE * M + sidE) * 2) : 0));         // 7
    int cF = cntF > 0 ? cntF : 1;
    int gjF = t0F + node; if (gjF > cF - 1) gjF = cF - 1; if (gjF < 0) gjF = 0;
    int sidF = sorted_idx[validF ? ((size_t)lF * M + offF + gjF) : 0]; // 8
    unsigned reB0 = ld_sys(flags + (lateB0 ? parB0 - NINIT : 0));      // 9
    unsigned reB1 = ld_sys(flags + (lateB1 ? parB1 - NINIT : 0));      // 10
    CBAR();

    // (L) fused derived-node loss from ot (pure VALU/LDS; overlaps the
    // in-flight store acks before the drain below).
    {
      const uint4 u = *(const uint4*)(ot + node * 136 + segq * 8);
      float pd = __uint_as_float(u.x << 16) * w8[0] +
                 __uint_as_float(u.x & 0xffff0000u) * w8[1] +
                 __uint_as_float(u.y << 16) * w8[2] +
                 __uint_as_float(u.y & 0xffff0000u) * w8[3] +
                 __uint_as_float(u.z << 16) * w8[4] +
                 __uint_as_float(u.z & 0xffff0000u) * w8[5] +
                 __uint_as_float(u.w << 16) * w8[6] +
                 __uint_as_float(u.w & 0xffff0000u) * w8[7];
      pd += __shfl_xor(pd, 1, 64);
      pd += __shfl_xor(pd, 2, 64);
      pd += __shfl_xor(pd, 4, 64);
      pd += __shfl_xor(pd, 8, 64);
      if (segq == 0 && (t0A + node) < cntA) {
        float logit = pd + eb;
        float tot = pPosA + pNegA, y = pPosA / tot;
        aP1 += tot * y * softplusf(-logit);
        aP2 += tot * (1.f - y) * softplusf(logit);
        if (logit >= 0.f) a_pos += pPosA; else a_neg += pNegA;
      }
    }

    // (5) ONE counted drain: rows are the oldest vmem ops; 10 loads were
    // issued after them, so vmcnt(10) <=> all rows at the LLC while the
    // prefetches stay in flight. Then ONE scatter publish: lanes 0-3 store
    // this wave's 4 node flags in a single instruction.
    asm volatile("s_waitcnt vmcnt(10)" ::: "memory");
    if (lane < 4) {
      int nd = wave + 8 * lane;
      int sidw = s_sid[p][nd];
      if ((t0A + nd) < cntA) st_sys(flags + lA * M + sidw, 1u);
    }
    CBAR();  // flags issued before any later spin

    // (6) shift pipeline slots (A<=B<=C<=E<=F<=cursor)
    lateA0 = lateB0; lateA1 = lateB1;
    reA0 = reB0; reA1 = reB1;
    gA0 = gB0; gA1 = gB1;
    parA0 = parB0; parA1 = parB1;
    pPosA = pPosB; pNegA = pNegB;
    lA = lB; t0A = t0B; cntA = cntB; validA = validB;

    parB0 = parC0; parB1 = parC1; sidB = sidC;
    fB0 = (validC && parC0 >= NINIT) ? pol0 : 1u;
    fB1 = (validC && parC1 >= NINIT) ? pol1 : 1u;
    pPosB = posC; pNegB = negC;
    lB = lC; t0B = t0C; cntB = cntC; validB = validC;

    parC0 = validE ? prE.x : 0; parC1 = validE ? prE.y : 0;
    sidC = sidE;
    lC = lE; t0C = t0E; cntC = cntE; validC = validE;

    sidE = sidF;
    lE = lF; t0E = t0F; cntE = cntF; validE = validF;

    validF = validF && adv_cursor(r, rule_off, lL, t0L, offL, cntL);
    lF = lL; t0F = t0L; offF = offL; cntF = cntL;
    p ^= 1;
  }

  // ---- Final reduction: wave shfl -> block LDS -> device atomics.
  for (int m = 32; m; m >>= 1) {
    aP1   += __shfl_xor(aP1,   m, 64);
    aP2   += __shfl_xor(aP2,   m, 64);
    a_pos += __shfl_xor(a_pos, m, 64);
    a_neg += __shfl_xor(a_neg, m, 64);
  }
  if (tid == 0) { racc[0] = 0.f; racc[1] = 0.f; racc[2] = 0.f; racc[3] = 0.f; }
  __syncthreads();
  if (lane == 0) {
    atomicAdd(&racc[0], aP1);
    atomicAdd(&racc[1], aP2);
    atomicAdd(&racc[2], a_pos);
    atomicAdd(&racc[3], a_neg);
  }
  __syncthreads();
  if (tid == 0) {
    atomicAdd(&out[0], pw * racc[0] + racc[1]);
    atomicAdd(&out[1], racc[2]);
    atomicAdd(&out[2], racc[3]);
  }
}

extern "C" void kernel_launch(void* const* d_in, const int* in_sizes, int n_in,
                              void* d_out, int out_size, void* d_ws, size_t ws_size,
                              hipStream_t stream) {
  const float* thax_table = (const float*)d_in[0];
  const float* sine_table = (const float*)d_in[1];
  const float* rule_W     = (const float*)d_in[2];
  const float* rule_b     = (const float*)d_in[3];
  const float* eval_w     = (const float*)d_in[4];
  const float* eval_b     = (const float*)d_in[5];
  const float* pos_vals   = (const float*)d_in[6];
  const float* neg_vals   = (const float*)d_in[7];
  const int*   init_thax  = (const int*)d_in[8];
  const int*   init_sine  = (const int*)d_in[9];
  const int*   parents    = (const int*)d_in[10];
  const int*   rules      = (const int*)d_in[11];

  float* out = (float*)d_out;
  char* ws = (char*)d_ws;
  float* sums = (float*)ws;                       // ws+0
  unsigned* bvars = (unsigned*)(ws + 128);        // barrier cnt/gen
  unsigned short* store = (unsigned short*)(ws + ST_OFF);
  int* sorted_idx = (int*)(ws + SI_OFF);
  int* rule_off   = (int*)(ws + RO_OFF);
  unsigned* flags = (unsigned*)(ws + FL_OFF);

  (void)hipMemsetAsync(d_out, 0, 3 * sizeof(float), stream);
  (void)hipMemsetAsync(d_ws, 0, 256, stream);                         // sums+bar
  (void)hipMemsetAsync(ws + FL_OFF, 0, (size_t)LVLS * M * 4, stream); // flags

  void* args[] = {&thax_table, &sine_table, &rule_W, &rule_b, &eval_w, &eval_b,
                  &pos_vals, &neg_vals, &init_thax, &init_sine, &parents,
                  &rules, &store, &sorted_idx, &rule_off, &flags, &sums,
                  &bvars, &out};
  (void)hipLaunchCooperativeKernel((void*)fused_kernel, dim3(NRULES),
                                   dim3(NTHR), args, 0, stream);
}